// Round 1
// baseline (277.756 us; speedup 1.0000x reference)
//
#include <hip/hip_runtime.h>

// out = (sum_p cos(w_p * phi_p) + (N - C)) / N,  N = next pow2 >= C.
// C = 2^25 here so N==C and the additive term is 0, but we compute it
// generically. Pure memory-bound reduction: 256 MiB read, 4 B write.

#define RBLOCKS 2048   // 8 blocks/CU on 256 CUs; d_ws needs RBLOCKS*4 B = 8 KiB
#define RTHREADS 256

__global__ __launch_bounds__(RTHREADS) void qs_partial_kernel(
    const float* __restrict__ phi, const float* __restrict__ w,
    float* __restrict__ partials, int n4, int n) {
    const float4* __restrict__ p4 = (const float4*)phi;
    const float4* __restrict__ w4 = (const float4*)w;

    float acc = 0.0f;
    int idx    = blockIdx.x * blockDim.x + threadIdx.x;
    int stride = gridDim.x * blockDim.x;
    for (int i = idx; i < n4; i += stride) {
        float4 a = p4[i];
        float4 b = w4[i];
        acc += __cosf(a.x * b.x);
        acc += __cosf(a.y * b.y);
        acc += __cosf(a.z * b.z);
        acc += __cosf(a.w * b.w);
    }
    // tail (n not divisible by 4) — single thread, tiny
    if (idx == 0) {
        for (int i = n4 * 4; i < n; ++i) acc += __cosf(phi[i] * w[i]);
    }

    // wave-64 shuffle reduce
    #pragma unroll
    for (int off = 32; off > 0; off >>= 1)
        acc += __shfl_down(acc, off, 64);

    __shared__ float smem[RTHREADS / 64];
    int lane = threadIdx.x & 63;
    int wid  = threadIdx.x >> 6;
    if (lane == 0) smem[wid] = acc;
    __syncthreads();
    if (threadIdx.x == 0) {
        float t = 0.0f;
        #pragma unroll
        for (int i = 0; i < RTHREADS / 64; ++i) t += smem[i];
        partials[blockIdx.x] = t;
    }
}

__global__ __launch_bounds__(1024) void qs_final_kernel(
    const float* __restrict__ partials, float* __restrict__ out,
    int nb, float addend, float inv_n) {
    float acc = 0.0f;
    for (int i = threadIdx.x; i < nb; i += blockDim.x) acc += partials[i];

    #pragma unroll
    for (int off = 32; off > 0; off >>= 1)
        acc += __shfl_down(acc, off, 64);

    __shared__ float smem[1024 / 64];
    int lane = threadIdx.x & 63;
    int wid  = threadIdx.x >> 6;
    if (lane == 0) smem[wid] = acc;
    __syncthreads();
    if (threadIdx.x == 0) {
        float t = 0.0f;
        #pragma unroll
        for (int i = 0; i < 1024 / 64; ++i) t += smem[i];
        out[0] = (t + addend) * inv_n;  // overwrites poisoned d_out every call
    }
}

extern "C" void kernel_launch(void* const* d_in, const int* in_sizes, int n_in,
                              void* d_out, int out_size, void* d_ws, size_t ws_size,
                              hipStream_t stream) {
    const float* phi = (const float*)d_in[0];
    const float* w   = (const float*)d_in[1];
    float* out       = (float*)d_out;
    float* partials  = (float*)d_ws;

    int n  = in_sizes[0];
    int n4 = n >> 2;

    // N = 2^ceil(log2(n))
    long long N = 1;
    while (N < (long long)n) N <<= 1;
    float addend = (float)(N - (long long)n);
    float inv_n  = 1.0f / (float)N;

    qs_partial_kernel<<<RBLOCKS, RTHREADS, 0, stream>>>(phi, w, partials, n4, n);
    qs_final_kernel<<<1, 1024, 0, stream>>>(partials, out, RBLOCKS, addend, inv_n);
}